// Round 2
// baseline (735.282 us; speedup 1.0000x reference)
//
#include <hip/hip_runtime.h>
#include <math.h>

#define BB 64
#define ID 10
#define MD 64
#define AD 16384
#define HCD 256
#define HRD 2
#define OD 8
#define PD 338
#define EPSF 1e-8f

// ---- output layout (floats), reference return order:
// logits[B,O], mem_new[B,M,A], rvs[B,HR,M], rws[B,HR,A], w_wr[B,A], h_new[B,HC], c_new[B,HC]
static constexpr size_t OFF_LOGITS = 0;
static constexpr size_t OFF_MEM = (size_t)BB * OD;                       // 512
static constexpr size_t OFF_RVS = OFF_MEM + (size_t)BB * MD * AD;        // 67109376
static constexpr size_t OFF_RWS = OFF_RVS + (size_t)BB * HRD * MD;       // 67117568
static constexpr size_t OFF_WWR = OFF_RWS + (size_t)BB * HRD * AD;       // 69214720
static constexpr size_t OFF_H   = OFF_WWR + (size_t)BB * AD;             // 70263296
static constexpr size_t OFF_C   = OFF_H + (size_t)BB * HCD;              // 70279680

// ---- workspace layout (floats)
// per-b params (stride 384): [0:64) kn_w  [64:128) erase  [128:192) add
// [192:256) kn_r0  [256:320) kn_r1
// [320]=beta_w [321]=g_w [322..324]=s_w [325]=gamma_w
// [326..331]=read0 (beta,g,s0,s1,s2,gamma)  [332..337]=read1
static constexpr size_t PAR = 0;
static constexpr size_t PAR_STR = 384;
static constexpr size_t EW   = PAR + (size_t)BB * PAR_STR;               // e buffer (write head) [B,A]
static constexpr size_t ER   = EW + (size_t)BB * AD;                     // e buffers (read heads) [2,B,A]
static constexpr size_t SUMS = ER + (size_t)2 * BB * AD;                 // per-b: 0 se_w 1 swp_w 2 se_r0 3 se_r1 4 swp_r0 5 swp_r1

__device__ __forceinline__ float sigmoidf_(float x) { return 1.f / (1.f + expf(-x)); }
__device__ __forceinline__ float softplusf_(float x) { return x > 20.f ? x : log1pf(expf(x)); }

// ---------------------------------------------------------------------------
// K1: LSTM + interface + param processing (one block per batch)
// ---------------------------------------------------------------------------
__global__ __launch_bounds__(256) void k_small(
    const float* __restrict__ inputs, const float* __restrict__ read_vecs,
    const float* __restrict__ h, const float* __restrict__ c,
    const float* __restrict__ W_ih, const float* __restrict__ W_hh,
    const float* __restrict__ b_lstm, const float* __restrict__ W_int,
    const float* __restrict__ b_int, const float* __restrict__ W_out,
    const float* __restrict__ b_out, float* __restrict__ out,
    float* __restrict__ ws)
{
  const int b = blockIdx.x;
  const int t = threadIdx.x;
  __shared__ float sx[144];
  __shared__ float sh[HCD];
  __shared__ float sg[4 * HCD];
  __shared__ float shn[HCD];
  __shared__ float sp[PD];

  if (t < ID) sx[t] = inputs[(size_t)b * ID + t];
  else if (t < ID + HRD * MD) sx[t] = read_vecs[(size_t)b * HRD * MD + (t - ID)];
  if (t < HCD) sh[t] = h[(size_t)b * HCD + t];
  // zero rv outputs + atomic sums for this batch
  if (t < HRD * MD) out[OFF_RVS + (size_t)b * HRD * MD + t] = 0.f;
  if (t >= 128 && t < 136) ws[SUMS + (size_t)b * 8 + (t - 128)] = 0.f;
  __syncthreads();

  // gates[j] = b + x @ W_ih[j,:] + h @ W_hh[j,:]
  const int LIN = ID + HRD * MD;  // 138
  #pragma unroll
  for (int q = 0; q < 4; ++q) {
    int j = t + q * 256;
    const float* wr = W_ih + (size_t)j * LIN;
    float acc = b_lstm[j];
    for (int k = 0; k < LIN; ++k) acc += sx[k] * wr[k];
    const float* wh = W_hh + (size_t)j * HCD;
    for (int k = 0; k < HCD; ++k) acc += sh[k] * wh[k];
    sg[j] = acc;
  }
  __syncthreads();

  // LSTM elementwise (t indexes hidden channel)
  {
    float ig = sg[t], fg = sg[t + 256], gg = sg[t + 512], og = sg[t + 768];
    float cv = c[(size_t)b * HCD + t];
    float cn = sigmoidf_(fg) * cv + sigmoidf_(ig) * tanhf(gg);
    float hn = sigmoidf_(og) * tanhf(cn);
    shn[t] = hn;
    out[OFF_C + (size_t)b * HCD + t] = cn;
    out[OFF_H + (size_t)b * HCD + t] = hn;
  }
  __syncthreads();

  // p = h_new @ W_int.T + b_int
  for (int j = t; j < PD; j += 256) {
    const float* wr = W_int + (size_t)j * HCD;
    float acc = b_int[j];
    for (int k = 0; k < HCD; ++k) acc += shn[k] * wr[k];
    sp[j] = acc;
  }
  // logits
  if (t < OD) {
    const float* wr = W_out + (size_t)t * HCD;
    float acc = b_out[t];
    for (int k = 0; k < HCD; ++k) acc += shn[k] * wr[k];
    out[OFF_LOGITS + (size_t)b * OD + t] = acc;
  }
  __syncthreads();

  // param processing
  float* par = ws + PAR + (size_t)b * PAR_STR;
  const int wv = t >> 6, lane = t & 63;
  if (wv < 3) {
    // wv==0: write head (p base 140, kn slot 0); wv==1/2: read heads 0/1
    const int base = (wv == 0) ? 140 : (wv - 1) * 70;
    const int slot = (wv == 0) ? 0 : (192 + (wv - 1) * 64);
    float kv = sp[base + lane];
    float ss = kv * kv;
    #pragma unroll
    for (int o = 32; o > 0; o >>= 1) ss += __shfl_xor(ss, o);
    par[slot + lane] = kv / (sqrtf(ss) + EPSF);
    if (lane == 0) {
      const int sb = (wv == 0) ? 320 : (326 + (wv - 1) * 6);
      float beta = softplusf_(sp[base + 64]);
      float g = sigmoidf_(sp[base + 65]);
      float s0 = sp[base + 66], s1 = sp[base + 67], s2 = sp[base + 68];
      float mx = fmaxf(s0, fmaxf(s1, s2));
      float e0 = expf(s0 - mx), e1 = expf(s1 - mx), e2 = expf(s2 - mx);
      float inv = 1.f / (e0 + e1 + e2);
      float gamma = 1.f + softplusf_(sp[base + 69]);
      par[sb + 0] = beta; par[sb + 1] = g;
      par[sb + 2] = e0 * inv; par[sb + 3] = e1 * inv; par[sb + 4] = e2 * inv;
      par[sb + 5] = gamma;
    }
  } else if (wv == 3) {
    par[64 + lane] = sigmoidf_(sp[210 + lane]);   // erase
    par[128 + lane] = sp[274 + lane];             // add
  }
}

// ---------------------------------------------------------------------------
// K2: write-head content sim over pre-update memory -> e = exp(beta*(sim-1))
// ---------------------------------------------------------------------------
__global__ __launch_bounds__(256) void k_wsim(const float* __restrict__ mem,
                                              float* __restrict__ ws)
{
  const int b = blockIdx.y;
  const int tid = threadIdx.x;
  const size_t a0 = (size_t)blockIdx.x * 1024 + (size_t)tid * 4;
  const float* par = ws + PAR + (size_t)b * PAR_STR;
  __shared__ float kn[MD];
  if (tid < MD) kn[tid] = par[tid];
  __syncthreads();

  const float* mb = mem + (size_t)b * MD * AD + a0;
  float4 ssq = make_float4(0.f, 0.f, 0.f, 0.f);
  float4 dt  = make_float4(0.f, 0.f, 0.f, 0.f);
  for (int m = 0; m < MD; ++m) {
    float4 v = *(const float4*)(mb + (size_t)m * AD);
    float kv = kn[m];
    ssq.x += v.x * v.x; ssq.y += v.y * v.y; ssq.z += v.z * v.z; ssq.w += v.w * v.w;
    dt.x += kv * v.x;  dt.y += kv * v.y;  dt.z += kv * v.z;  dt.w += kv * v.w;
  }
  const float beta = par[320];
  float4 e;
  e.x = expf(beta * (dt.x / (sqrtf(ssq.x) + EPSF) - 1.f));
  e.y = expf(beta * (dt.y / (sqrtf(ssq.y) + EPSF) - 1.f));
  e.z = expf(beta * (dt.z / (sqrtf(ssq.z) + EPSF) - 1.f));
  e.w = expf(beta * (dt.w / (sqrtf(ssq.w) + EPSF) - 1.f));
  *(float4*)(ws + EW + (size_t)b * AD + a0) = e;

  float s = e.x + e.y + e.z + e.w;
  #pragma unroll
  for (int o = 32; o > 0; o >>= 1) s += __shfl_xor(s, o);
  __shared__ float red[4];
  if ((tid & 63) == 0) red[tid >> 6] = s;
  __syncthreads();
  if (tid == 0) atomicAdd(ws + SUMS + (size_t)b * 8 + 0, red[0] + red[1] + red[2] + red[3]);
}

// ---------------------------------------------------------------------------
// K3: write head: interpolate + circular shift + sharpen -> wp (unnormalized)
// ---------------------------------------------------------------------------
__global__ __launch_bounds__(256) void k_wsharp(const float* __restrict__ write_w,
                                                float* __restrict__ out,
                                                float* __restrict__ ws)
{
  const int b = blockIdx.y;
  const int tid = threadIdx.x;
  const int a0 = blockIdx.x * 1024 + tid * 4;
  const float* par = ws + PAR + (size_t)b * PAR_STR;
  const float g = par[321], s0 = par[322], s1 = par[323], s2 = par[324], gamma = par[325];
  const float inv_se = 1.f / ws[SUMS + (size_t)b * 8 + 0];
  const float* e = ws + EW + (size_t)b * AD;
  const float* wprev = write_w + (size_t)b * AD;

  float wg[6];
  #pragma unroll
  for (int i = 0; i < 6; ++i) {
    int a = (a0 - 1 + i) & (AD - 1);
    wg[i] = g * e[a] * inv_se + (1.f - g) * wprev[a];
  }
  float4 wp;
  wp.x = powf(s0 * wg[2] + s1 * wg[1] + s2 * wg[0] + EPSF, gamma);
  wp.y = powf(s0 * wg[3] + s1 * wg[2] + s2 * wg[1] + EPSF, gamma);
  wp.z = powf(s0 * wg[4] + s1 * wg[3] + s2 * wg[2] + EPSF, gamma);
  wp.w = powf(s0 * wg[5] + s1 * wg[4] + s2 * wg[3] + EPSF, gamma);
  *(float4*)(out + OFF_WWR + (size_t)b * AD + a0) = wp;

  float s = wp.x + wp.y + wp.z + wp.w;
  #pragma unroll
  for (int o = 32; o > 0; o >>= 1) s += __shfl_xor(s, o);
  __shared__ float red[4];
  if ((tid & 63) == 0) red[tid >> 6] = s;
  __syncthreads();
  if (tid == 0) atomicAdd(ws + SUMS + (size_t)b * 8 + 1, red[0] + red[1] + red[2] + red[3]);
}

// ---------------------------------------------------------------------------
// K4: normalize w_wr, memory update, and read-head sims over mem_new (fused)
// ---------------------------------------------------------------------------
__global__ __launch_bounds__(256) void k_update(const float* __restrict__ mem,
                                                float* __restrict__ out,
                                                float* __restrict__ ws)
{
  const int b = blockIdx.y;
  const int tid = threadIdx.x;
  const size_t a0 = (size_t)blockIdx.x * 1024 + (size_t)tid * 4;
  const float* par = ws + PAR + (size_t)b * PAR_STR;
  __shared__ float se[MD], sa[MD], sk0[MD], sk1[MD];
  if (tid < MD) {
    se[tid] = par[64 + tid]; sa[tid] = par[128 + tid];
    sk0[tid] = par[192 + tid]; sk1[tid] = par[256 + tid];
  }
  __syncthreads();

  const float invw = 1.f / (ws[SUMS + (size_t)b * 8 + 1] + EPSF);
  float* wwr = out + OFF_WWR + (size_t)b * AD + a0;
  float4 w = *(float4*)wwr;
  w.x *= invw; w.y *= invw; w.z *= invw; w.w *= invw;
  *(float4*)wwr = w;

  const float* mb = mem + (size_t)b * MD * AD + a0;
  float* nb = out + OFF_MEM + (size_t)b * MD * AD + a0;
  float4 ssq = make_float4(0.f, 0.f, 0.f, 0.f);
  float4 d0 = make_float4(0.f, 0.f, 0.f, 0.f);
  float4 d1 = make_float4(0.f, 0.f, 0.f, 0.f);
  for (int m = 0; m < MD; ++m) {
    float4 v = *(const float4*)(mb + (size_t)m * AD);
    float er = se[m], ad = sa[m], k0 = sk0[m], k1 = sk1[m];
    float4 nv;
    nv.x = v.x * (1.f - er * w.x) + ad * w.x;
    nv.y = v.y * (1.f - er * w.y) + ad * w.y;
    nv.z = v.z * (1.f - er * w.z) + ad * w.z;
    nv.w = v.w * (1.f - er * w.w) + ad * w.w;
    *(float4*)(nb + (size_t)m * AD) = nv;
    ssq.x += nv.x * nv.x; ssq.y += nv.y * nv.y; ssq.z += nv.z * nv.z; ssq.w += nv.w * nv.w;
    d0.x += k0 * nv.x; d0.y += k0 * nv.y; d0.z += k0 * nv.z; d0.w += k0 * nv.w;
    d1.x += k1 * nv.x; d1.y += k1 * nv.y; d1.z += k1 * nv.z; d1.w += k1 * nv.w;
  }
  const float b0 = par[326], b1 = par[332];
  float4 e0, e1;
  e0.x = expf(b0 * (d0.x / (sqrtf(ssq.x) + EPSF) - 1.f));
  e0.y = expf(b0 * (d0.y / (sqrtf(ssq.y) + EPSF) - 1.f));
  e0.z = expf(b0 * (d0.z / (sqrtf(ssq.z) + EPSF) - 1.f));
  e0.w = expf(b0 * (d0.w / (sqrtf(ssq.w) + EPSF) - 1.f));
  e1.x = expf(b1 * (d1.x / (sqrtf(ssq.x) + EPSF) - 1.f));
  e1.y = expf(b1 * (d1.y / (sqrtf(ssq.y) + EPSF) - 1.f));
  e1.z = expf(b1 * (d1.z / (sqrtf(ssq.z) + EPSF) - 1.f));
  e1.w = expf(b1 * (d1.w / (sqrtf(ssq.w) + EPSF) - 1.f));
  *(float4*)(ws + ER + ((size_t)0 * BB + b) * AD + a0) = e0;
  *(float4*)(ws + ER + ((size_t)1 * BB + b) * AD + a0) = e1;

  float p0 = e0.x + e0.y + e0.z + e0.w;
  float p1 = e1.x + e1.y + e1.z + e1.w;
  #pragma unroll
  for (int o = 32; o > 0; o >>= 1) { p0 += __shfl_xor(p0, o); p1 += __shfl_xor(p1, o); }
  __shared__ float red[8];
  const int lane = tid & 63, wv = tid >> 6;
  if (lane == 0) { red[wv] = p0; red[4 + wv] = p1; }
  __syncthreads();
  if (tid == 0) atomicAdd(ws + SUMS + (size_t)b * 8 + 2, red[0] + red[1] + red[2] + red[3]);
  if (tid == 1) atomicAdd(ws + SUMS + (size_t)b * 8 + 3, red[4] + red[5] + red[6] + red[7]);
}

// ---------------------------------------------------------------------------
// K5: read heads: interpolate + shift + sharpen -> wp into rws slot
// ---------------------------------------------------------------------------
__global__ __launch_bounds__(256) void k_rsharp(const float* __restrict__ read_w,
                                                float* __restrict__ out,
                                                float* __restrict__ ws)
{
  const int b = blockIdx.y;
  const int hH = blockIdx.z;
  const int tid = threadIdx.x;
  const int a0 = blockIdx.x * 1024 + tid * 4;
  const float* par = ws + PAR + (size_t)b * PAR_STR;
  const int sb = 326 + hH * 6;
  const float g = par[sb + 1], s0 = par[sb + 2], s1 = par[sb + 3], s2 = par[sb + 4], gamma = par[sb + 5];
  const float inv_se = 1.f / ws[SUMS + (size_t)b * 8 + 2 + hH];
  const float* e = ws + ER + ((size_t)hH * BB + b) * AD;
  const float* wprev = read_w + ((size_t)b * HRD + hH) * AD;

  float wg[6];
  #pragma unroll
  for (int i = 0; i < 6; ++i) {
    int a = (a0 - 1 + i) & (AD - 1);
    wg[i] = g * e[a] * inv_se + (1.f - g) * wprev[a];
  }
  float4 wp;
  wp.x = powf(s0 * wg[2] + s1 * wg[1] + s2 * wg[0] + EPSF, gamma);
  wp.y = powf(s0 * wg[3] + s1 * wg[2] + s2 * wg[1] + EPSF, gamma);
  wp.z = powf(s0 * wg[4] + s1 * wg[3] + s2 * wg[2] + EPSF, gamma);
  wp.w = powf(s0 * wg[5] + s1 * wg[4] + s2 * wg[3] + EPSF, gamma);
  *(float4*)(out + OFF_RWS + ((size_t)b * HRD + hH) * AD + a0) = wp;

  float s = wp.x + wp.y + wp.z + wp.w;
  #pragma unroll
  for (int o = 32; o > 0; o >>= 1) s += __shfl_xor(s, o);
  __shared__ float red[4];
  if ((tid & 63) == 0) red[tid >> 6] = s;
  __syncthreads();
  if (tid == 0) atomicAdd(ws + SUMS + (size_t)b * 8 + 4 + hH, red[0] + red[1] + red[2] + red[3]);
}

// ---------------------------------------------------------------------------
// K6: normalize rws in place + read vectors (one pass over mem_new)
// ---------------------------------------------------------------------------
__global__ __launch_bounds__(256) void k_readvec(float* __restrict__ out,
                                                 const float* __restrict__ ws)
{
  const int b = blockIdx.y;
  const int tid = threadIdx.x;
  const size_t a0 = (size_t)blockIdx.x * 1024 + (size_t)tid * 4;
  const float inv0 = 1.f / (ws[SUMS + (size_t)b * 8 + 4] + EPSF);
  const float inv1 = 1.f / (ws[SUMS + (size_t)b * 8 + 5] + EPSF);

  float* r0 = out + OFF_RWS + ((size_t)b * HRD + 0) * AD + a0;
  float* r1 = out + OFF_RWS + ((size_t)b * HRD + 1) * AD + a0;
  float4 w0 = *(float4*)r0;
  w0.x *= inv0; w0.y *= inv0; w0.z *= inv0; w0.w *= inv0;
  *(float4*)r0 = w0;
  float4 w1 = *(float4*)r1;
  w1.x *= inv1; w1.y *= inv1; w1.z *= inv1; w1.w *= inv1;
  *(float4*)r1 = w1;

  const float* mn = out + OFF_MEM + (size_t)b * MD * AD + a0;
  __shared__ float part[4][MD][2];
  const int lane = tid & 63, wv = tid >> 6;
  for (int m = 0; m < MD; ++m) {
    float4 v = *(const float4*)(mn + (size_t)m * AD);
    float p0 = v.x * w0.x + v.y * w0.y + v.z * w0.z + v.w * w0.w;
    float p1 = v.x * w1.x + v.y * w1.y + v.z * w1.z + v.w * w1.w;
    #pragma unroll
    for (int o = 32; o > 0; o >>= 1) { p0 += __shfl_xor(p0, o); p1 += __shfl_xor(p1, o); }
    if (lane == 0) { part[wv][m][0] = p0; part[wv][m][1] = p1; }
  }
  __syncthreads();
  if (tid < 128) {
    int hH = tid >> 6, m = tid & 63;
    float s = part[0][m][hH] + part[1][m][hH] + part[2][m][hH] + part[3][m][hH];
    atomicAdd(out + OFF_RVS + ((size_t)b * HRD + hH) * MD + m, s);
  }
}

// ---------------------------------------------------------------------------
extern "C" void kernel_launch(void* const* d_in, const int* in_sizes, int n_in,
                              void* d_out, int out_size, void* d_ws, size_t ws_size,
                              hipStream_t stream) {
  const float* inputs    = (const float*)d_in[0];
  const float* memory    = (const float*)d_in[1];
  const float* read_w    = (const float*)d_in[2];
  const float* write_w   = (const float*)d_in[3];
  const float* h         = (const float*)d_in[4];
  const float* c         = (const float*)d_in[5];
  const float* read_vecs = (const float*)d_in[6];
  const float* W_ih      = (const float*)d_in[7];
  const float* W_hh      = (const float*)d_in[8];
  const float* b_lstm    = (const float*)d_in[9];
  const float* W_int     = (const float*)d_in[10];
  const float* b_int     = (const float*)d_in[11];
  const float* W_out     = (const float*)d_in[12];
  const float* b_out     = (const float*)d_in[13];
  float* out = (float*)d_out;
  float* ws  = (float*)d_ws;

  hipLaunchKernelGGL(k_small, dim3(BB), dim3(256), 0, stream,
                     inputs, read_vecs, h, c, W_ih, W_hh, b_lstm, W_int, b_int,
                     W_out, b_out, out, ws);
  hipLaunchKernelGGL(k_wsim, dim3(AD / 1024, BB), dim3(256), 0, stream, memory, ws);
  hipLaunchKernelGGL(k_wsharp, dim3(AD / 1024, BB), dim3(256), 0, stream, write_w, out, ws);
  hipLaunchKernelGGL(k_update, dim3(AD / 1024, BB), dim3(256), 0, stream, memory, out, ws);
  hipLaunchKernelGGL(k_rsharp, dim3(AD / 1024, BB, HRD), dim3(256), 0, stream, read_w, out, ws);
  hipLaunchKernelGGL(k_readvec, dim3(AD / 1024, BB), dim3(256), 0, stream, out, ws);
}